// Round 2
// baseline (175.831 us; speedup 1.0000x reference)
//
#include <hip/hip_runtime.h>
#include <stdint.h>

// Problem constants (from reference):
//   features: [128, 16384, 6] f32; mask_token: [6] f32; seed 1234
//   MASK_RATIO=0.15 -> target_masked = int(16384*0.15) = 2457
//   n_spans = max(1, int(2457/12.5*2)) = 393
constexpr int NB = 128;
constexpr int SEQ = 16384;
constexpr int NF = 6;
constexpr int NSPANS = 393;
constexpr uint32_t TGT = 2457u;
constexpr int ROWF = SEQ * NF;          // 98304 floats per row
constexpr int ROWF4 = ROWF / 4;         // 24576 float4 per row
constexpr int TOT4 = NB * ROWF4;        // 3145728 float4 total

struct Keys {
  uint32_t klo0, klo1;   // randint(k_len) child-2 key -> lower bits (span=16 pow2: only these matter)
  uint32_t khi_s0, khi_s1; // randint(k_start) child-1 key -> higher bits
  uint32_t klo_s0, klo_s1; // randint(k_start) child-2 key -> lower bits
  uint32_t kn0, kn1;       // k_noise
};

// JAX threefry2x32 (20 rounds)
__host__ __device__ inline void tf2x32(uint32_t k0, uint32_t k1,
                                       uint32_t x0, uint32_t x1,
                                       uint32_t& o0, uint32_t& o1) {
  uint32_t ks[3] = {k0, k1, k0 ^ k1 ^ 0x1BD11BDAu};
  uint32_t a = x0 + ks[0], b = x1 + ks[1];
  const uint32_t rot[2][4] = {{13u,15u,26u,6u},{17u,29u,16u,24u}};
#pragma unroll
  for (int i = 0; i < 5; ++i) {
    const uint32_t* r = rot[i & 1];
#pragma unroll
    for (int j = 0; j < 4; ++j) {
      a += b;
      b = (b << r[j]) | (b >> (32u - r[j]));
      b ^= a;
    }
    a += ks[(i + 1) % 3];
    b += ks[(i + 2) % 3] + (uint32_t)(i + 1);
  }
  o0 = a; o1 = b;
}

// JAX partitionable random_bits (32-bit): bits[j] = a ^ b, (a,b) = tf(key, (0, j))
__device__ inline uint32_t rbits(uint32_t k0, uint32_t k1, uint32_t j) {
  uint32_t o0, o1;
  tf2x32(k0, k1, 0u, j, o0, o1);
  return o0 ^ o1;
}

__device__ inline uint32_t score_int(const Keys& K, uint32_t b, int s,
                                     const uint32_t* cov) {
  uint32_t j = b * (uint32_t)SEQ + (uint32_t)s;
  uint32_t bits = rbits(K.kn0, K.kn1, j);
  // noise = m*2^-23 with m = bits>>9; score = coverage + noise  ->  exact 24-bit int
  return (bits >> 9) + (((cov[s >> 5] >> (s & 31)) & 1u) << 23);
}

__global__ __launch_bounds__(256)
void mask_kernel(const float* __restrict__ feat, const float* __restrict__ tok,
                 float* __restrict__ out, uint32_t* __restrict__ maskws,
                 int fused, Keys K) {
  __shared__ uint32_t cov[SEQ / 32];   // span coverage bits
  __shared__ uint32_t fm[SEQ / 32];    // final mask bits
  __shared__ uint32_t hist[4096];
  __shared__ uint32_t part[256];
  __shared__ uint32_t sH, sA, sT, sN;

  const int t = threadIdx.x;
  const uint32_t b = blockIdx.x;

  for (int i = t; i < 4096; i += 256) hist[i] = 0u;
  for (int i = t; i < SEQ / 32; i += 256) cov[i] = 0u;
  __syncthreads();

  // ---- spans: lengths = 5 + (low & 15); starts = randint(0, 16379) ----
  for (int i = t; i < NSPANS; i += 256) {
    uint32_t j = b * (uint32_t)NSPANS + (uint32_t)i;
    uint32_t lenb = rbits(K.klo0, K.klo1, j);
    uint32_t len = 5u + (lenb & 15u);
    uint32_t hb = rbits(K.khi_s0, K.khi_s1, j);
    uint32_t lb = rbits(K.klo_s0, K.klo_s1, j);
    const uint32_t span = 16379u;
    // value = hi*2^32 + lo; value % span via multiplier (2^32 % span) = 400
    uint32_t start = ((hb % span) * 400u + (lb % span)) % span;
    uint32_t end = start + len; if (end > (uint32_t)SEQ) end = SEQ;
    uint32_t w0 = start >> 5, w1 = (end - 1u) >> 5;
    for (uint32_t w = w0; w <= w1; ++w) {
      uint32_t bs = (w == w0) ? (start & 31u) : 0u;
      uint32_t be = (w == w1) ? ((end - 1u) & 31u) : 31u;
      uint32_t n = be - bs + 1u;
      uint32_t m = (n >= 32u) ? 0xFFFFFFFFu : (((1u << n) - 1u) << bs);
      atomicOr(&cov[w], m);
    }
  }
  __syncthreads();

  // ---- pass A: histogram of si>>12 ----
  for (int q = 0; q < 64; ++q) {
    int s = t + (q << 8);
    uint32_t si = score_int(K, b, s, cov);
    atomicAdd(&hist[si >> 12], 1u);
  }
  __syncthreads();
  {
    uint32_t sum = 0;
#pragma unroll
    for (int i = 0; i < 16; ++i) sum += hist[t * 16 + i];
    part[t] = sum;
    __syncthreads();
    for (int off = 1; off < 256; off <<= 1) {
      uint32_t v = (t + off < 256) ? part[t + off] : 0u;
      __syncthreads();
      part[t] += v;
      __syncthreads();
    }
    uint32_t above = (t < 255) ? part[t + 1] : 0u;  // count of si in higher chunks
    uint32_t mine = part[t];
    if (above < TGT && TGT <= mine) {
      uint32_t run = above;
      for (int hb = t * 16 + 15; hb >= t * 16; --hb) {
        uint32_t c = hist[hb];
        if (run + c >= TGT) { sH = (uint32_t)hb; sA = run; break; }
        run += c;
      }
    }
  }
  __syncthreads();
  uint32_t H = sH;
  uint32_t targetB = TGT - sA;

  // ---- pass B: histogram of low 12 bits within bucket H ----
  for (int i = t; i < 4096; i += 256) hist[i] = 0u;
  __syncthreads();
  for (int q = 0; q < 64; ++q) {
    int s = t + (q << 8);
    uint32_t si = score_int(K, b, s, cov);
    if ((si >> 12) == H) atomicAdd(&hist[si & 4095u], 1u);
  }
  __syncthreads();
  {
    uint32_t sum = 0;
#pragma unroll
    for (int i = 0; i < 16; ++i) sum += hist[t * 16 + i];
    part[t] = sum;
    __syncthreads();
    for (int off = 1; off < 256; off <<= 1) {
      uint32_t v = (t + off < 256) ? part[t + off] : 0u;
      __syncthreads();
      part[t] += v;
      __syncthreads();
    }
    uint32_t above = (t < 255) ? part[t + 1] : 0u;
    uint32_t mine = part[t];
    if (above < targetB && targetB <= mine) {
      uint32_t run = above;
      for (int lb = t * 16 + 15; lb >= t * 16; --lb) {
        uint32_t c = hist[lb];
        if (run + c >= targetB) {
          sT = (H << 12) | (uint32_t)lb;
          sN = targetB - run;   // # of ties at T to accept (lowest indices first)
          break;
        }
        run += c;
      }
    }
  }
  __syncthreads();
  uint32_t T = sT, need = sN;

  // ---- pass C: accept si>T, plus first `need` ties (ascending index); AND valid ----
  const float* rowf = feat + (size_t)b * ROWF;
  {
    int base = t << 6;   // contiguous 64-position chunk per thread
    uint32_t cnt = 0;
    for (int i = 0; i < 64; ++i) {
      uint32_t si = score_int(K, b, base + i, cov);
      cnt += (si == T) ? 1u : 0u;
    }
    part[t] = cnt;
    __syncthreads();
    for (int off = 1; off < 256; off <<= 1) {
      uint32_t v = (t >= off) ? part[t - off] : 0u;
      __syncthreads();
      part[t] += v;
      __syncthreads();
    }
    uint32_t r = part[t] - cnt;   // ties before my chunk
    uint32_t w0 = 0, w1 = 0;
    for (int i = 0; i < 64; ++i) {
      int s = base + i;
      uint32_t si = score_int(K, b, s, cov);
      bool tie = (si == T);
      bool a = (si > T) || (tie && r < need);
      r += tie ? 1u : 0u;
      float f0 = rowf[s * 6];
      a = a && !(f0 != f0);      // valid = !isnan(features[b,s,0])
      if (i < 32) w0 |= ((uint32_t)a) << i;
      else        w1 |= ((uint32_t)a) << (i - 32);
    }
    fm[2 * t] = w0;
    fm[2 * t + 1] = w1;
  }
  __syncthreads();

  if (!fused) {
    maskws[b * (SEQ / 32) + 2 * t] = fm[2 * t];
    maskws[b * (SEQ / 32) + 2 * t + 1] = fm[2 * t + 1];
    return;
  }

  // ---- fused apply (fallback when ws too small) ----
  float tk[NF];
#pragma unroll
  for (int c = 0; c < NF; ++c) tk[c] = tok[c];
  float* rowo = out + (size_t)b * ROWF;
  const float4* rf4 = (const float4*)rowf;
  float4* ro4 = (float4*)rowo;
  for (int q = t; q < ROWF4; q += 256) {
    float4 v = rf4[q];
    float vv[4] = {v.x, v.y, v.z, v.w};
    int e = q * 4;
#pragma unroll
    for (int k = 0; k < 4; ++k) {
      int ee = e + k;
      int p = ee / 6;
      int c = ee - p * 6;
      if ((fm[p >> 5] >> (p & 31)) & 1u) vv[k] = tk[c];
    }
    ro4[q] = make_float4(vv[0], vv[1], vv[2], vv[3]);
  }
}

__global__ __launch_bounds__(256)
void apply_kernel(const float* __restrict__ feat, const float* __restrict__ tok,
                  const uint32_t* __restrict__ maskws, float* __restrict__ out) {
  float tk[NF];
#pragma unroll
  for (int c = 0; c < NF; ++c) tk[c] = tok[c];
  const float4* f4 = (const float4*)feat;
  float4* o4 = (float4*)out;
  int stride = gridDim.x * 256;
  for (int q = blockIdx.x * 256 + threadIdx.x; q < TOT4; q += stride) {
    float4 v = f4[q];
    int e0 = q * 4;
    int b = e0 / ROWF;
    int e = e0 - b * ROWF;
    const uint32_t* fm = maskws + b * (SEQ / 32);
    float vv[4] = {v.x, v.y, v.z, v.w};
#pragma unroll
    for (int k = 0; k < 4; ++k) {
      int ee = e + k;
      int p = ee / 6;
      int c = ee - p * 6;
      if ((fm[p >> 5] >> (p & 31)) & 1u) vv[k] = tk[c];
    }
    o4[q] = make_float4(vv[0], vv[1], vv[2], vv[3]);
  }
}

extern "C" void kernel_launch(void* const* d_in, const int* in_sizes, int n_in,
                              void* d_out, int out_size, void* d_ws, size_t ws_size,
                              hipStream_t stream) {
  const float* feat = (const float*)d_in[0];
  const float* tok = (const float*)d_in[1];
  float* out = (float*)d_out;

  // ---- host-side key derivation (partitionable threefry, mirrors modern JAX) ----
  // key(1234) -> raw (0, 1234)
  // split(key, 3) foldlike: child i = tf(key, (0, i)), full output pair is the child key
  uint32_t klen0, klen1, kst0, kst1, kn0, kn1;
  tf2x32(0u, 1234u, 0u, 0u, klen0, klen1);   // k_len
  tf2x32(0u, 1234u, 0u, 1u, kst0, kst1);     // k_start
  tf2x32(0u, 1234u, 0u, 2u, kn0, kn1);       // k_noise

  // randint internal split(key, 2): k1 = tf(key,(0,0)) -> higher_bits,
  //                                 k2 = tf(key,(0,1)) -> lower_bits
  uint32_t lh0, lh1, ll0, ll1;
  tf2x32(klen0, klen1, 0u, 0u, lh0, lh1);    // k_len child 1 (unused: span=16 pow2)
  tf2x32(klen0, klen1, 0u, 1u, ll0, ll1);    // k_len child 2 -> lower bits
  (void)lh0; (void)lh1;
  uint32_t sh0, sh1, sl0, sl1;
  tf2x32(kst0, kst1, 0u, 0u, sh0, sh1);      // k_start child 1 -> higher bits
  tf2x32(kst0, kst1, 0u, 1u, sl0, sl1);      // k_start child 2 -> lower bits

  Keys K{ ll0, ll1, sh0, sh1, sl0, sl1, kn0, kn1 };

  bool two = ws_size >= (size_t)(NB * (SEQ / 32) * 4);
  if (two) {
    hipLaunchKernelGGL(mask_kernel, dim3(NB), dim3(256), 0, stream,
                       feat, tok, out, (uint32_t*)d_ws, 0, K);
    hipLaunchKernelGGL(apply_kernel, dim3(2048), dim3(256), 0, stream,
                       feat, tok, (const uint32_t*)d_ws, out);
  } else {
    hipLaunchKernelGGL(mask_kernel, dim3(NB), dim3(256), 0, stream,
                       feat, tok, out, nullptr, 1, K);
  }
}